// Round 2
// baseline (101.505 us; speedup 1.0000x reference)
//
#include <hip/hip_runtime.h>
#include <cmath>

#define KCLS 10
#define NCELL 3721          // 61*61
#define BIGV  0x0FFFFFFF

// d_out layout (all float32), concatenated in reference return order
#define OUT_PROB 0
#define OUT_LAB  37210
#define OUT_BOX  74420
#define OUT_VALID 223300

// ---------------------------------------------------------------------------
// DPP wave64 sum on the VALU pipe (v_add_f32_dpp); result lands in lane 63.
#define DPPADD(x, ctrl) \
    x += __int_as_float(__builtin_amdgcn_update_dpp( \
        0, __float_as_int(x), ctrl, 0xf, 0xf, true))

__device__ __forceinline__ float wave_sum64(float x) {
    DPPADD(x, 0x111);   // row_shr:1
    DPPADD(x, 0x112);   // row_shr:2
    DPPADD(x, 0x114);   // row_shr:4
    DPPADD(x, 0x118);   // row_shr:8
    DPPADD(x, 0x142);   // row_bcast:15
    DPPADD(x, 0x143);   // row_bcast:31
    return x;           // lane 63 holds the 64-lane sum
}

// Swizzled LDS float-index for W element j (row = j/10, col = j%10).
// Rows padded to 16 floats; 16B slot s of row r stored at s ^ ((r>>1)&3):
// over 8 consecutive rows a fixed column slot spreads across all 32 banks ->
// conflict-free ds_read_b128 when 64 lanes read 64 consecutive rows.
__device__ __forceinline__ int swz_fidx(int j) {
    const int row = j / 10;
    const int c   = j - row * 10;
    return (row << 4) + (((c >> 2) ^ ((row >> 1) & 3)) << 2) + (c & 3);
}

// ---------------- Stage 1: patch GEMM (+bias) + softmax --------------------
// 488 blocks x 512 threads (61 patch-rows x 8 col-groups). Threads = 256
// d-lanes x 2 class-halves; each thread: 8 patches x 5 classes -> acc[8][5]
// = 40 VGPRs (total ~90, far under the 128 cap at 2 blocks/CU -> no spill,
// and ~2 independent blocks/CU decouple the per-iteration barrier drain).
// Per K-step: W rows [it*256,+256) staged coalesced (dwordx4) into a
// swizzled double-buffered LDS tile (32 KiB); x read direct (L1-resident).
__global__ __launch_bounds__(512, 4) void k1_logits(
    const float* __restrict__ x, const float* __restrict__ W,
    const float* __restrict__ b, float* __restrict__ out)
{
    const int tid  = threadIdx.x;
    const int tsub = tid & 255;       // d-lane
    const int kh   = tid >> 8;        // class half: kh=0 -> k0..4, kh=1 -> k5..9
    const int r    = blockIdx.x >> 3;            // 0..60 exact
    const int cg   = blockIdx.x & 7;
    const int c0   = (cg == 7) ? 53 : cg * 8;    // cols c0..c0+7 all <= 60

    __shared__ float  wbuf[2][256 * 16];         // 32 KiB swizzled W tiles
    __shared__ float  red[8][8][5];              // [wave][patch][class5]
    __shared__ double lgs[8][KCLS];

    // staging: 2560 floats/tile; thread owns float4 @ j0 and float @ 2048+tid
    const int j0 = tid << 2;
    const int d0 = swz_fidx(j0);                 // (j0, j0+1) pair — never straddles a row
    const int d1 = swz_fidx(j0 + 2);             // (j0+2, j0+3) pair
    const int je = 2048 + tid;
    const int d2 = swz_fidx(je);

    // compute-side read offsets (row = tsub, it-invariant)
    const int s3 = (tsub >> 1) & 3;
    const int rb = tsub << 4;
    const int q0 = rb + ((0 ^ s3) << 2);         // slot0: f0..f3
    const int q1 = rb + ((1 ^ s3) << 2);         // slot1: f4..f7
    const int q2 = rb + ((2 ^ s3) << 2);         // slot2: f8..f9

    // x addressing: d = tsub + it*256 = i*192 + rem
    int i   = (tsub >= 192) ? 1 : 0;
    int rem = tsub - i * 192;
    const float* xb = x + r * 49152 + c0 * 48;

    float acc[8][5];
#pragma unroll
    for (int p = 0; p < 8; ++p)
#pragma unroll
        for (int k = 0; k < 5; ++k) acc[p][k] = 0.0f;

    // prologue: stage tile 0, prefetch tile 1 into regs
    float4 sv; float s1;
    {
        const float4 v0 = *(const float4*)(W + j0);
        const float  v1 = W[je];
        float* wb0 = &wbuf[0][0];
        *(float2*)(wb0 + d0) = make_float2(v0.x, v0.y);
        *(float2*)(wb0 + d1) = make_float2(v0.z, v0.w);
        wb0[d2] = v1;
        const float* ws = W + 2560;
        sv = *(const float4*)(ws + j0);
        s1 = ws[je];
    }

    for (int it = 0; it < 48; ++it) {
        __syncthreads();    // prev compute done -> safe to write other buffer
        if (it + 1 < 48) {
            float* wbn = &wbuf[(it + 1) & 1][0];
            *(float2*)(wbn + d0) = make_float2(sv.x, sv.y);
            *(float2*)(wbn + d1) = make_float2(sv.z, sv.w);
            wbn[d2] = s1;
            if (it + 2 < 48) {   // issue-early: hides under this iter's compute
                const float* ws = W + (it + 2) * 2560;
                sv = *(const float4*)(ws + j0);
                s1 = ws[je];
            }
        }
        // x loads issued first (TA pipe), consumed after LDS reads
        const float* xp = xb + i * 3072 + rem;
        float xv[8];
#pragma unroll
        for (int p = 0; p < 8; ++p) xv[p] = xp[p * 48];

        const float* wb = &wbuf[it & 1][0];
        float wv[5];
        if (kh == 0) {                            // wave-uniform branch
            const float4 a = *(const float4*)(wb + q0);
            wv[0] = a.x; wv[1] = a.y; wv[2] = a.z; wv[3] = a.w;
            wv[4] = wb[q1];
        } else {
            const float4 a = *(const float4*)(wb + q1);
            const float2 c = *(const float2*)(wb + q2);
            wv[0] = a.y; wv[1] = a.z; wv[2] = a.w; wv[3] = c.x; wv[4] = c.y;
        }
#pragma unroll
        for (int p = 0; p < 8; ++p)
#pragma unroll
            for (int k = 0; k < 5; ++k) acc[p][k] += xv[p] * wv[k];

        rem += 64; ++i;                  // d += 256
        if (rem >= 192) { rem -= 192; ++i; }
    }

    // wave reduction (VALU pipe), partials to LDS
    const int w = tid >> 6;              // wave = kh*4 + (tsub>>6)
#pragma unroll
    for (int p = 0; p < 8; ++p)
#pragma unroll
        for (int k = 0; k < 5; ++k) {
            const float s = wave_sum64(acc[p][k]);
            if ((tid & 63) == 63) red[w][p][k] = s;
        }
    __syncthreads();

    if (tid < 80) {
        const int p  = tid / 10;
        const int kk = tid - p * 10;
        const int khk = (kk >= 5) ? 1 : 0;
        const int k5  = kk - khk * 5;
        double s = (double)b[kk];
#pragma unroll
        for (int j = 0; j < 4; ++j) s += (double)red[khk * 4 + j][p][k5];
        lgs[p][kk] = s;
    }
    __syncthreads();

    if (tid < 8) {
        const int cc = c0 + tid;          // overlap cols recompute bit-identically
        double l[KCLS];
#pragma unroll
        for (int k = 0; k < KCLS; ++k) l[k] = lgs[tid][k];
        double m = l[0];
#pragma unroll
        for (int k = 1; k < KCLS; ++k) m = fmax(m, l[k]);
        double e[KCLS], ssum = 0.0;
#pragma unroll
        for (int k = 0; k < KCLS; ++k) { e[k] = exp(l[k] - m); ssum += e[k]; }
        const double inv = 1.0 / ssum;
        float* po = out + OUT_PROB + (size_t)(r * 61 + cc) * KCLS;
#pragma unroll
        for (int k = 0; k < KCLS; ++k) po[k] = (float)(e[k] * inv);
    }
}

// ---------------- Stage 2+3 fused: CC (union-find hooking) + boxes ---------
// One block per class. Labels stored as LDS OFFSETS (off = (r+1)*64 + c+1):
// min-off == min-idx (both lexicographic in (r,c)). Root chase + atomicMin
// hooking = path compression -> ~3-6 rounds instead of O(diameter).
__global__ __launch_bounds__(1024) void k2_cc_boxes(float* __restrict__ out)
{
    const int k   = blockIdx.x;
    const int tid = threadIdx.x;

    __shared__ int lab[63 * 64];
    __shared__ int act[NCELL];
    __shared__ int nact, changed;
    __shared__ int rmn[NCELL + 1], rmx[NCELL + 1], cmn[NCELL + 1], cmx[NCELL + 1];

    for (int idx = tid; idx < 63 * 64; idx += 1024) lab[idx] = BIGV;
    for (int s = tid; s <= NCELL; s += 1024) {
        rmn[s] = 0x7fffffff; cmn[s] = 0x7fffffff; rmx[s] = -1; cmx[s] = -1;
    }
    if (tid == 0) nact = 0;
    __syncthreads();

    for (int idx = tid; idx < NCELL; idx += 1024) {
        const float pv = out[OUT_PROB + (size_t)idx * KCLS + k];
        if (pv > 0.7f) {
            const int r = idx / 61, c = idx - r * 61;
            const int off = (r + 1) * 64 + (c + 1);
            lab[off] = off;
            act[atomicAdd(&nact, 1)] = off;
        }
    }
    __syncthreads();
    const int na = nact;

    for (int round = 0; round < 128; ++round) {
        if (tid == 0) changed = 0;
        __syncthreads();
        bool ch = false;
        for (int ii = tid; ii < na; ii += 1024) {
            const int off = act[ii];
            const int v = lab[off];
            int m = v, t;
            t = lab[off - 1];  if (t < m) m = t;
            t = lab[off + 1];  if (t < m) m = t;
            t = lab[off - 64]; if (t < m) m = t;
            t = lab[off + 64]; if (t < m) m = t;
            if (m < v) {
                int p = lab[m];                       // chase to current root
                while (p < m) { m = p; p = lab[m]; }  // strictly decreasing
                atomicMin(&lab[off], m);              // compress self
                atomicMin(&lab[v],   m);              // hook old root (union)
                ch = true;
            }
        }
        if (ch) changed = 1;       // benign race
        __syncthreads();
        if (changed == 0) break;   // no writes between the barriers -> uniform
        __syncthreads();           // protect next round's reset
    }

    // write labels (convert off -> idx+1)
    for (int idx = tid; idx < NCELL; idx += 1024) {
        const int r = idx / 61, c = idx - r * 61;
        const int v = lab[(r + 1) * 64 + (c + 1)];
        const int lv = (v < BIGV) ? ((v >> 6) * 61 - 61 + (v & 63)) : 0;
        out[OUT_LAB + (size_t)idx * KCLS + k] = (float)lv;
    }

    // boxes: segment min/max over active cells only
    for (int ii = tid; ii < na; ii += 1024) {
        const int off = act[ii];
        const int v = lab[off];
        const int lb = (v >> 6) * 61 - 61 + (v & 63);
        const int r = (off >> 6) - 1, c = (off & 63) - 1;
        atomicMin(&rmn[lb], r); atomicMax(&rmx[lb], r);
        atomicMin(&cmn[lb], c); atomicMax(&cmx[lb], c);
    }
    __syncthreads();

    for (int s = tid; s <= NCELL; s += 1024) {
        const bool val = (s > 0) && (rmx[s] >= 0);
        float* bo = out + OUT_BOX + (size_t)(k * (NCELL + 1) + s) * 4;
        if (val) {
            bo[0] = (float)(rmn[s] - 1);
            bo[1] = (float)(cmn[s] - 1);
            bo[2] = (float)(rmx[s] + 1);
            bo[3] = (float)(cmx[s] + 1);
        } else {
            bo[0] = 0.0f; bo[1] = 0.0f; bo[2] = 0.0f; bo[3] = 0.0f;
        }
        out[OUT_VALID + (size_t)k * (NCELL + 1) + s] = val ? 1.0f : 0.0f;
    }
}

extern "C" void kernel_launch(void* const* d_in, const int* in_sizes, int n_in,
                              void* d_out, int out_size, void* d_ws, size_t ws_size,
                              hipStream_t stream) {
    const float* x = (const float*)d_in[0];   // (1,1024,1024,3) f32
    const float* W = (const float*)d_in[1];   // (12288,10) f32
    const float* b = (const float*)d_in[2];   // (10,) f32
    float* out = (float*)d_out;

    k1_logits  <<<dim3(488), dim3(512), 0, stream>>>(x, W, b, out);
    k2_cc_boxes<<<dim3(KCLS), dim3(1024), 0, stream>>>(out);
}

// Round 3
// 93.760 us; speedup vs baseline: 1.0826x; 1.0826x over previous
//
#include <hip/hip_runtime.h>
#include <cmath>

#define KCLS 10
#define NCELL 3721          // 61*61
#define BIGV  0x0FFFFFFF

// d_out layout (all float32), concatenated in reference return order
#define OUT_PROB 0
#define OUT_LAB  37210
#define OUT_BOX  74420
#define OUT_VALID 223300

// padded pixel-row: raw float index p stored at p + 4*(p/48).
// Read pattern addr = 52*(c+tq) + 4u -> dword-bank 20*(c+tq)+4u mod 32 walks
// all 8 bank-quads with period 8 -> conflict-free-optimal ds_read_b128.
#define XROW_PAD 3328       // 3072 + 4*64

// helper: element n (compile-time after unroll) of a float4[10] block
#define WF(q, n) ( ((n)&3)==0 ? (q)[(n)>>2].x : ((n)&3)==1 ? (q)[(n)>>2].y : \
                   ((n)&3)==2 ? (q)[(n)>>2].z : (q)[(n)>>2].w )

// ---------------- Stage 1a: partial logits ---------------------------------
// Grid 1952 = 61 patch-rows x 32 i-pairs; 256 threads = 4 waves (t-quarters).
// Lane = patch column c (61 used). For each d = i*192 + t, W[d][0..9] is
// wave-uniform -> s_load into SGPRs (scalar pipe); x comes from one LDS-staged
// padded pixel row via conflict-free ds_read_b128. Inner step per wave:
// 1 ds_read_b128 + 10 s_load_dwordx4 + 40 v_fma  -> FMA-bound.
__global__ __launch_bounds__(256, 4) void k1a_partial(
    const float* __restrict__ x, const float* __restrict__ W,
    float* __restrict__ partial)
{
    const int tid  = threadIdx.x;
    const int bid  = blockIdx.x;          // 0..1951
    const int i2   = bid / 61;            // 0..31  (i-pair)
    const int r    = bid - i2 * 61;       // 0..60  (patch row)
    const int lane = tid & 63;
    const int tq   = tid >> 6;            // t-quarter 0..3
    const int tqu  = __builtin_amdgcn_readfirstlane(tq);
    const int cc   = (lane < 61) ? lane : 60;   // dup lanes, write-guarded

    __shared__ float xrow[2][XROW_PAD];
    __shared__ float red[4][61][KCLS];

    // stage the two pixel rows (16r + 2*i2 + ii), padded
#pragma unroll
    for (int ii = 0; ii < 2; ++ii) {
        const float* g = x + (size_t)((r << 4) + (i2 << 1) + ii) * 3072;
#pragma unroll
        for (int j = 0; j < 3; ++j) {
            const int idx = tid + (j << 8);       // 0..767 float4s
            const float4 v = *(const float4*)(g + (idx << 2));
            const int p = idx << 2;               // p%48 <= 44 -> same pad for all 4
            float* d = &xrow[ii][p + ((p / 48) << 2)];
            d[0] = v.x; d[1] = v.y; d[2] = v.z; d[3] = v.w;
        }
    }
    __syncthreads();

    float acc[KCLS];
#pragma unroll
    for (int k = 0; k < KCLS; ++k) acc[k] = 0.0f;

#pragma unroll
    for (int ii = 0; ii < 2; ++ii) {
        const int dbase = ((i2 << 1) + ii) * 192 + tqu * 48;   // + 4u
        const float* wrow = W + (size_t)dbase * KCLS;          // uniform -> s_load
        const float* lrow = &xrow[ii][52 * (cc + tqu)];        // + 4u
#pragma unroll
        for (int u = 0; u < 12; ++u) {
            const float4 xv = *(const float4*)(lrow + (u << 2));
            const float* wp = wrow + 40 * u;       // 160B-aligned
            float4 wq[10];
#pragma unroll
            for (int j = 0; j < 10; ++j) wq[j] = *(const float4*)(wp + (j << 2));
#pragma unroll
            for (int k = 0; k < KCLS; ++k) {
                acc[k] += xv.x * WF(wq, k);        // d+0
                acc[k] += xv.y * WF(wq, 10 + k);   // d+1
                acc[k] += xv.z * WF(wq, 20 + k);   // d+2
                acc[k] += xv.w * WF(wq, 30 + k);   // d+3
            }
        }
    }

    if (lane < 61) {
#pragma unroll
        for (int k = 0; k < KCLS; ++k) red[tq][lane][k] = acc[k];
    }
    __syncthreads();

    // cross-wave (t-quarter) reduce, store 610 contiguous floats
    for (int t = tid; t < 610; t += 256) {
        const int c = t / 10, k = t - c * 10;
        const float s = red[0][c][k] + red[1][c][k] + red[2][c][k] + red[3][c][k];
        partial[(size_t)i2 * 37210 + (size_t)r * 610 + (size_t)c * 10 + k] = s;
    }
}

// ---------------- Stage 1b: reduce partials + bias + softmax ---------------
__global__ __launch_bounds__(640) void k1b_softmax(
    const float* __restrict__ partial, const float* __restrict__ b,
    float* __restrict__ out)
{
    const int r   = blockIdx.x;           // 0..60
    const int tid = threadIdx.x;
    __shared__ double lgs[61][KCLS];

    if (tid < 610) {
        const int c = tid / 10, k = tid - c * 10;
        double s = (double)b[k];
        const float* p = partial + (size_t)r * 610 + tid;
#pragma unroll 8
        for (int i2 = 0; i2 < 32; ++i2)
            s += (double)p[(size_t)i2 * 37210];
        lgs[c][k] = s;
    }
    __syncthreads();

    if (tid < 61) {
        double l[KCLS];
#pragma unroll
        for (int k = 0; k < KCLS; ++k) l[k] = lgs[tid][k];
        double m = l[0];
#pragma unroll
        for (int k = 1; k < KCLS; ++k) m = fmax(m, l[k]);
        double e[KCLS], ssum = 0.0;
#pragma unroll
        for (int k = 0; k < KCLS; ++k) { e[k] = exp(l[k] - m); ssum += e[k]; }
        const double inv = 1.0 / ssum;
        float* po = out + OUT_PROB + (size_t)(r * 61 + tid) * KCLS;
#pragma unroll
        for (int k = 0; k < KCLS; ++k) po[k] = (float)(e[k] * inv);
    }
}

// ---------------- Stage 2+3 fused: CC (union-find hooking) + boxes ---------
// One block per class. Labels stored as LDS OFFSETS (off = (r+1)*64 + c+1):
// min-off == min-idx (both lexicographic in (r,c)). Root chase + atomicMin
// hooking = path compression -> ~3-6 rounds instead of O(diameter).
__global__ __launch_bounds__(1024) void k2_cc_boxes(float* __restrict__ out)
{
    const int k   = blockIdx.x;
    const int tid = threadIdx.x;

    __shared__ int lab[63 * 64];
    __shared__ int act[NCELL];
    __shared__ int nact, changed;
    __shared__ int rmn[NCELL + 1], rmx[NCELL + 1], cmn[NCELL + 1], cmx[NCELL + 1];

    for (int idx = tid; idx < 63 * 64; idx += 1024) lab[idx] = BIGV;
    for (int s = tid; s <= NCELL; s += 1024) {
        rmn[s] = 0x7fffffff; cmn[s] = 0x7fffffff; rmx[s] = -1; cmx[s] = -1;
    }
    if (tid == 0) nact = 0;
    __syncthreads();

    for (int idx = tid; idx < NCELL; idx += 1024) {
        const float pv = out[OUT_PROB + (size_t)idx * KCLS + k];
        if (pv > 0.7f) {
            const int r = idx / 61, c = idx - r * 61;
            const int off = (r + 1) * 64 + (c + 1);
            lab[off] = off;
            act[atomicAdd(&nact, 1)] = off;
        }
    }
    __syncthreads();
    const int na = nact;

    for (int round = 0; round < 128; ++round) {
        if (tid == 0) changed = 0;
        __syncthreads();
        bool ch = false;
        for (int ii = tid; ii < na; ii += 1024) {
            const int off = act[ii];
            const int v = lab[off];
            int m = v, t;
            t = lab[off - 1];  if (t < m) m = t;
            t = lab[off + 1];  if (t < m) m = t;
            t = lab[off - 64]; if (t < m) m = t;
            t = lab[off + 64]; if (t < m) m = t;
            if (m < v) {
                int p = lab[m];                       // chase to current root
                while (p < m) { m = p; p = lab[m]; }  // strictly decreasing
                atomicMin(&lab[off], m);              // compress self
                atomicMin(&lab[v],   m);              // hook old root (union)
                ch = true;
            }
        }
        if (ch) changed = 1;       // benign race
        __syncthreads();
        if (changed == 0) break;   // no writes between the barriers -> uniform
        __syncthreads();           // protect next round's reset
    }

    // write labels (convert off -> idx+1)
    for (int idx = tid; idx < NCELL; idx += 1024) {
        const int r = idx / 61, c = idx - r * 61;
        const int v = lab[(r + 1) * 64 + (c + 1)];
        const int lv = (v < BIGV) ? ((v >> 6) * 61 - 61 + (v & 63)) : 0;
        out[OUT_LAB + (size_t)idx * KCLS + k] = (float)lv;
    }

    // boxes: segment min/max over active cells only
    for (int ii = tid; ii < na; ii += 1024) {
        const int off = act[ii];
        const int v = lab[off];
        const int lb = (v >> 6) * 61 - 61 + (v & 63);
        const int r = (off >> 6) - 1, c = (off & 63) - 1;
        atomicMin(&rmn[lb], r); atomicMax(&rmx[lb], r);
        atomicMin(&cmn[lb], c); atomicMax(&cmx[lb], c);
    }
    __syncthreads();

    for (int s = tid; s <= NCELL; s += 1024) {
        const bool val = (s > 0) && (rmx[s] >= 0);
        float* bo = out + OUT_BOX + (size_t)(k * (NCELL + 1) + s) * 4;
        if (val) {
            bo[0] = (float)(rmn[s] - 1);
            bo[1] = (float)(cmn[s] - 1);
            bo[2] = (float)(rmx[s] + 1);
            bo[3] = (float)(cmx[s] + 1);
        } else {
            bo[0] = 0.0f; bo[1] = 0.0f; bo[2] = 0.0f; bo[3] = 0.0f;
        }
        out[OUT_VALID + (size_t)k * (NCELL + 1) + s] = val ? 1.0f : 0.0f;
    }
}

extern "C" void kernel_launch(void* const* d_in, const int* in_sizes, int n_in,
                              void* d_out, int out_size, void* d_ws, size_t ws_size,
                              hipStream_t stream) {
    const float* x = (const float*)d_in[0];   // (1,1024,1024,3) f32
    const float* W = (const float*)d_in[1];   // (12288,10) f32
    const float* b = (const float*)d_in[2];   // (10,) f32
    float* out     = (float*)d_out;
    float* partial = (float*)d_ws;            // 32*61*61*10 f32 = 4.77 MB

    k1a_partial<<<dim3(1952), dim3(256), 0, stream>>>(x, W, partial);
    k1b_softmax<<<dim3(61),   dim3(640), 0, stream>>>(partial, b, out);
    k2_cc_boxes<<<dim3(KCLS), dim3(1024), 0, stream>>>(out);
}